// Round 13
// baseline (289.751 us; speedup 1.0000x reference)
//
#include <hip/hip_runtime.h>

#define SS 730
#define GG 4000
#define LENF 15
#define PD 10          // prefetch depth (steps); 730 % 10 == 0
#define GPAD 4096      // per-instance thread range; 4*4096 = 16 blocks of 1024
#define TT 10          // route time-tile; 730 % 10 == 0 (TT=73 spilled, r12)
#define QN ((size_t)SS * GG)
#define QNI ((int)(SS * GG))

// ---------------------------------------------------------------------------
// Scan kernel, round-13: DENSE-BLOCK launch for wave co-residency.
// Body = round-7 exact (best per-wave floor). The change is the launch shape:
// 16 blocks x 1024 threads -> each block = 16 waves on ONE CU = 4 waves per
// SIMD. The SIMD's round-robin issue interleaves 4 independent scan waves,
// filling each wave's ~160 cyc/step dependency bubbles with other waves'
// instructions -- the interleave that in-thread ILP (rounds 4/8/10/11)
// could not achieve. inst = tid/GPAD (block-aligned: every block is pure
// HBV or pure EXP); g = tid % GPAD, guarded to g < GG.
// ---------------------------------------------------------------------------
template<bool STORE4>
__global__ __launch_bounds__(1024, 1) void hydro_scan(const float* __restrict__ x,
                                                      const float* __restrict__ raw,
                                                      float* __restrict__ qsim) {
    int tid = blockIdx.x * 1024 + threadIdx.x;
    int g = tid % GPAD;
    int inst = tid / GPAD;
    if (g >= GG) return;
    int m = inst & 1;
    const float* pr = raw + (size_t)g * 38 + m;   // pr[2*i] = raw[g, i*2+m]

    int xoff = g * 3;
    int qoff = g + (STORE4 ? inst * QNI : 0);

    // prefetch pipeline: steps 0..PD-1
    float pb[PD], tb[PD], eb[PD];
#pragma unroll
    for (int j = 0; j < PD; ++j) {
        pb[j] = x[xoff]; tb[j] = x[xoff + 1]; eb[j] = x[xoff + 2];
        xoff += 3 * GG;
    }

    if (inst < 2) {
        // ---- HBV parameters (descale + derived constants) ----
        float beta  = 1.0f   + pr[0]  * 5.0f;
        float fc    = 50.0f  + pr[2]  * 950.0f;
        float k0    = 0.05f  + pr[4]  * 0.85f;
        float k1    = 0.01f  + pr[6]  * 0.49f;
        float k2    = 0.001f + pr[8]  * 0.199f;
        float lp    = 0.2f   + pr[10] * 0.8f;
        float perc  =          pr[12] * 10.0f;
        float uzl   =          pr[14] * 100.0f;
        float tt    = -2.5f  + pr[16] * 5.0f;
        float cfmax = 0.5f   + pr[18] * 9.5f;
        float cfr   =          pr[20] * 0.1f;
        float cwh   =          pr[22] * 0.2f;
        float invfc   = 1.0f / fc;
        float invlpfc = 1.0f / (lp * fc);
        float ncfrcf  = -(cfr * cfmax);
        float omk0    = 1.0f - k0;
        float k0uzl   = k0 * uzl;
        float omk1    = 1.0f - k1;

        float sp = 1e-5f, mw = 1e-5f, sm = 0.5f * fc, suz = 1e-5f, slz = 1e-5f;

        auto body = [&](float p, float tc, float pet) -> float {
            // off-chain (forcing-only) terms
            float dt   = tc - tt;
            float msn  = fmaxf(cfmax * dt, 0.0f);
            float mrf  = fmaxf(ncfrcf * dt, 0.0f);
            float rain = (dt >= 0.0f) ? p : 0.0f;
            float snow = p - rain;
            float etk  = fmaf(-invlpfc, pet, 1.0f);      // 1 - pet/(lp*fc)
            // long pole first: sw from previous-step sm
            float sw   = exp2f(beta * __log2f(sm * invfc));   // <= 1 (sm<=fc)
            float omsw = 1.0f - sw;
            // snow / melt-water chains
            float sp1  = sp + snow;
            float melt = fminf(msn, sp1);
            float mw2  = mw + melt;
            float sp2  = sp1 - melt;
            float refr = fminf(mrf, mw2);
            float mw3  = mw2 - refr;
            sp = sp2 + refr;
            float mw4  = fminf(mw3, cwh * sp);
            float tosoil = mw3 - mw4;
            mw = mw4;
            // soil moisture
            float rt    = rain + tosoil;
            float sm1   = fmaf(rt, omsw, sm);            // sm + rt - rech
            float rech  = rt * sw;
            float excess = fmaxf(sm1 - fc, 0.0f);
            float sm2   = fminf(sm1, fc);
            sm = fmaxf(fmaxf(sm2 * etk, sm2 - pet), 1e-5f);   // v_max3
            // upper / lower zones
            float suz1 = suz + rech + excess;
            float suz2 = fmaxf(suz1 - perc, 0.0f);
            float pa   = suz1 - suz2;                    // = min(perc, suz1)
            float suz3 = fminf(suz2, fmaf(suz2, omk0, k0uzl));
            float suzn = omk1 * suz3;
            float q01  = suz2 - suzn;                    // q0 + q1
            suz = suzn;
            float slz1 = slz + pa;
            float q2   = k2 * slz1;
            slz = slz1 - q2;
            return q01 + q2;
        };

        for (int c = 0; c < SS / PD - 1; ++c) {
#pragma unroll
            for (int j = 0; j < PD; ++j) {
                float p = pb[j], tc = tb[j], pet = eb[j];
                pb[j] = x[xoff]; tb[j] = x[xoff + 1]; eb[j] = x[xoff + 2];
                xoff += 3 * GG;
                float q = body(p, tc, pet);
                if (STORE4) qsim[qoff] = q; else atomicAdd(&qsim[qoff], 0.25f * q);
                qoff += GG;
            }
        }
#pragma unroll
        for (int j = 0; j < PD; ++j) {           // peeled last chunk
            float q = body(pb[j], tb[j], eb[j]);
            if (STORE4) qsim[qoff] = q; else atomicAdd(&qsim[qoff], 0.25f * q);
            qoff += GG;
        }
    } else {
        // ---- EXP-HYDRO parameters (descale + derived constants) ----
        const float* pe = pr + 24;
        float f    =           pe[0]  * 0.1f;
        float smax = 100.0f  + pe[2]  * 1400.0f;
        float qmax = 10.0f   + pe[4]  * 40.0f;
        float df   =           pe[6]  * 5.0f;
        float tmax =           pe[8]  * 3.0f;
        float tmin = -3.0f   + pe[10] * 3.0f;
        float invsmax = 1.0f / smax;
        float fl = f * 1.44269504f;              // f * log2(e)
        float c0 = __log2f(qmax) - fl * smax;    // fold qmax into exponent

        float s0 = 1e-5f, s1 = 0.5f * smax;

        auto body = [&](float p, float tc, float pet) -> float {
            // off-chain terms
            float mdf = df * fmaxf(tc - tmax, 0.0f);
            float ps  = (tc <= tmin) ? p : 0.0f;
            float prr = p - ps;
            float etk = fmaxf(fmaf(-invsmax, pet, 1.0f), 0.0f);
            // chains
            float mlt = fminf(s0, mdf);
            s0 = fmaxf(s0 - mdf, 0.0f) + ps;
            float s1a = s1 + prr + mlt;
            float qspill = fmaxf(s1a - smax, 0.0f);
            float s1b = fminf(s1a, smax);
            float s1c = s1b * etk;                       // s1b - et (exact)
            float qb  = fminf(exp2f(fmaf(fl, s1c, c0)), s1c);
            s1 = s1c - qb;
            return qspill + qb;
        };

        for (int c = 0; c < SS / PD - 1; ++c) {
#pragma unroll
            for (int j = 0; j < PD; ++j) {
                float p = pb[j], tc = tb[j], pet = eb[j];
                pb[j] = x[xoff]; tb[j] = x[xoff + 1]; eb[j] = x[xoff + 2];
                xoff += 3 * GG;
                float q = body(p, tc, pet);
                if (STORE4) qsim[qoff] = q; else atomicAdd(&qsim[qoff], 0.25f * q);
                qoff += GG;
            }
        }
#pragma unroll
        for (int j = 0; j < PD; ++j) {
            float q = body(pb[j], tb[j], eb[j]);
            if (STORE4) qsim[qoff] = q; else atomicAdd(&qsim[qoff], 0.25f * q);
            qoff += GG;
        }
    }
}

// ---------------------------------------------------------------------------
// UH weights: one thread per g, 15 normalized gamma-UH weights once (0.25
// folded). gammaln cancels: w[k] ∝ exp((aa-1)ln(k+.5)-(k+.5)/th).
// ---------------------------------------------------------------------------
__global__ __launch_bounds__(256) void uh_weights(const float* __restrict__ raw,
                                                  float* __restrict__ wbuf) {
    int g = blockIdx.x * 256 + threadIdx.x;
    if (g >= GG) return;
    float a = raw[(size_t)g * 38 + 36] * 2.9f;
    float b = raw[(size_t)g * 38 + 37] * 6.5f;
    float aa = fmaxf(a, 0.0f) + 0.1f;
    float th = fmaxf(b, 0.0f) + 0.5f;
    float am1 = aa - 1.0f;
    float invth = 1.0f / th;

    const float logt[LENF] = {
        -0.69314718f, 0.40546511f, 0.91629073f, 1.25276297f, 1.50407740f,
         1.70474809f, 1.87180218f, 2.01490302f, 2.14006616f, 2.25129180f,
         2.35137526f, 2.44234704f, 2.52572864f, 2.60268969f, 2.67414865f };

    float w[LENF];
    float s = 0.0f;
#pragma unroll
    for (int k = 0; k < LENF; ++k) {
        float tk = (float)k + 0.5f;
        w[k] = expf(am1 * logt[k] - tk * invth);
        s += w[k];
    }
    float scale = 0.25f / s;
#pragma unroll
    for (int k = 0; k < LENF; ++k)
        wbuf[(size_t)k * GG + g] = w[k] * scale;
}

// ---------------------------------------------------------------------------
// Routing kernel, t-tiled (TT=10, register-safe). Each thread owns one g and
// TT consecutive t's. WPRE: weights preloaded from wbuf (scale folded).
// ---------------------------------------------------------------------------
template<int NB, bool WPRE>
__global__ __launch_bounds__(256) void hydro_route(const float* __restrict__ qsim,
                                                   const float* __restrict__ raw,
                                                   const float* __restrict__ wbuf,
                                                   float* __restrict__ out) {
    int idx = blockIdx.x * 256 + threadIdx.x;
    if (idx >= GG * (SS / TT)) return;
    int g = idx % GG;          // g fast -> coalesced
    int c = idx / GG;
    int t0 = c * TT;

    float w[LENF];
    float scale;
    if (WPRE) {
#pragma unroll
        for (int k = 0; k < LENF; ++k)
            w[k] = wbuf[(size_t)k * GG + g];
        scale = 1.0f;
    } else {
        float a = raw[(size_t)g * 38 + 36] * 2.9f;
        float b = raw[(size_t)g * 38 + 37] * 6.5f;
        float aa = fmaxf(a, 0.0f) + 0.1f;
        float th = fmaxf(b, 0.0f) + 0.5f;
        float am1 = aa - 1.0f;
        float invth = 1.0f / th;
        const float logt[LENF] = {
            -0.69314718f, 0.40546511f, 0.91629073f, 1.25276297f, 1.50407740f,
             1.70474809f, 1.87180218f, 2.01490302f, 2.14006616f, 2.25129180f,
             2.35137526f, 2.44234704f, 2.52572864f, 2.60268969f, 2.67414865f };
        float s = 0.0f;
#pragma unroll
        for (int k = 0; k < LENF; ++k) {
            float tk = (float)k + 0.5f;
            w[k] = expf(am1 * logt[k] - tk * invth);
            s += w[k];
        }
        scale = (NB == 4 ? 0.25f : 1.0f) / s;
    }

    // load qsim[t0-14 .. t0+TT-1] (zeros before t=0), summing NB slices
    float v[TT + LENF - 1];
#pragma unroll
    for (int i = 0; i < TT + LENF - 1; ++i) {
        int tp = t0 - (LENF - 1) + i;
        float sv = 0.0f;
        if (tp >= 0) {
            const float* qb = qsim + (size_t)tp * GG + g;
            sv = qb[0];
            if (NB == 4) sv += qb[QN] + qb[2 * QN] + qb[3 * QN];
        }
        v[i] = sv;
    }
#pragma unroll
    for (int j = 0; j < TT; ++j) {
        float acc = 0.0f;
#pragma unroll
        for (int k = 0; k < LENF; ++k)
            acc += w[k] * v[j + (LENF - 1) - k];
        out[(size_t)(t0 + j) * GG + g] = (WPRE ? acc : acc * scale);
    }
}

// ---------------------------------------------------------------------------
extern "C" void kernel_launch(void* const* d_in, const int* in_sizes, int n_in,
                              void* d_out, int out_size, void* d_ws, size_t ws_size,
                              hipStream_t stream) {
    const float* x   = (const float*)d_in[0];   // (730, 4000, 3) f32
    const float* raw = (const float*)d_in[1];   // (4000, 38) f32
    float* out  = (float*)d_out;                // (730, 4000) f32
    float* qsim = (float*)d_ws;

    const size_t slices4 = 4 * QN * sizeof(float);
    const size_t wbytes  = (size_t)LENF * GG * sizeof(float);
    int rblocks = (GG * (SS / TT) + 255) / 256;
    int sblocks = (4 * GPAD) / 1024;            // 16 blocks x 1024 threads

    if (ws_size >= slices4 + wbytes) {
        float* wbuf = qsim + 4 * QN;
        hydro_scan<true><<<sblocks, 1024, 0, stream>>>(x, raw, qsim);
        uh_weights<<<(GG + 255) / 256, 256, 0, stream>>>(raw, wbuf);
        hydro_route<4, true><<<rblocks, 256, 0, stream>>>(qsim, raw, wbuf, out);
    } else {
        hipMemsetAsync(qsim, 0, QN * sizeof(float), stream);
        hydro_scan<false><<<sblocks, 1024, 0, stream>>>(x, raw, qsim);
        hydro_route<1, false><<<rblocks, 256, 0, stream>>>(qsim, raw, nullptr, out);
    }
}

// Round 14
// 124.121 us; speedup vs baseline: 2.3344x; 2.3344x over previous
//
#include <hip/hip_runtime.h>

#define SS 730
#define GG 4000
#define LENF 15
#define PD 10          // prefetch depth (steps); 730 % 10 == 0
#define GPAD 4032      // 63 waves per instance -> no wave mixes models
#define TT 10          // route time-tile (atomic-fallback path only)
#define QN ((size_t)SS * GG)
#define QNI ((int)(SS * GG))

// ---------------------------------------------------------------------------
// Scan kernel, round-14: r7 scan (proven floor: ~290 cyc/step = max(issue
// ~177, chain ~290); rounds 4/8/10/11/13 bracketed it from every direction)
// + FUSED ROUTING. The ~113 idle issue cyc/step absorb a 15-tap circular
// partial-accumulation: q[t] scatters w[k]*q into racc[(t+k)%15]; slot t%15
// completes at step t and is stored as the ROUTED partial r_i[t]. Slot
// indices are compile-time via 30-step (lcm(10,15)) outer unroll. Final
// out = r0+r1+r2+r3 is a trivial elementwise sum kernel (58 MB traffic vs
// the old route kernel's ~124 MB) -- the uh_weights kernel disappears
// (each thread computes its 15 normalized weights once; gammaln cancels).
// ---------------------------------------------------------------------------
template<bool FUSED>
__global__ __launch_bounds__(64, 1) void hydro_scan(const float* __restrict__ x,
                                                    const float* __restrict__ raw,
                                                    float* __restrict__ qsim) {
    int tid = blockIdx.x * 64 + threadIdx.x;
    int g = tid % GPAD;
    int inst = tid / GPAD;
    if (g >= GG) return;
    int m = inst & 1;
    const float* pr = raw + (size_t)g * 38 + m;   // pr[2*i] = raw[g, i*2+m]

    int xoff = g * 3;
    int qoff = g + (FUSED ? inst * QNI : 0);

    // ---- per-thread normalized UH weights (0.25 instance-average folded) ----
    float w[LENF];
    if (FUSED) {
        const float logt[LENF] = {
            -0.69314718f, 0.40546511f, 0.91629073f, 1.25276297f, 1.50407740f,
             1.70474809f, 1.87180218f, 2.01490302f, 2.14006616f, 2.25129180f,
             2.35137526f, 2.44234704f, 2.52572864f, 2.60268969f, 2.67414865f };
        float a = raw[(size_t)g * 38 + 36] * 2.9f;
        float b = raw[(size_t)g * 38 + 37] * 6.5f;
        float aa = fmaxf(a, 0.0f) + 0.1f;
        float th = fmaxf(b, 0.0f) + 0.5f;
        float am1 = aa - 1.0f;
        float invth = 1.0f / th;
        float s = 0.0f;
#pragma unroll
        for (int k = 0; k < LENF; ++k) {
            float tk = (float)k + 0.5f;
            w[k] = expf(am1 * logt[k] - tk * invth);
            s += w[k];
        }
        float ws = 0.25f / s;
#pragma unroll
        for (int k = 0; k < LENF; ++k) w[k] *= ws;
    }
    float racc[LENF];
#pragma unroll
    for (int k = 0; k < LENF; ++k) racc[k] = 0.0f;

    // prefetch pipeline: steps 0..PD-1
    float pb[PD], tb[PD], eb[PD];
#pragma unroll
    for (int j = 0; j < PD; ++j) {
        pb[j] = x[xoff]; tb[j] = x[xoff + 1]; eb[j] = x[xoff + 2];
        xoff += 3 * GG;
    }

    // fused routing tail: slot s = t % 15 completes at step t
    auto route_tail = [&](float q, int s) {      // s is compile-time
        float o = fmaf(w[0], q, racc[s]);
        qsim[qoff] = o;                          // routed partial r_i[t]
        qoff += GG;
        racc[s] = 0.0f;
#pragma unroll
        for (int k = 1; k < LENF; ++k)
            racc[(s + k) % LENF] = fmaf(w[k], q, racc[(s + k) % LENF]);
    };

    if (inst < 2) {
        // ---- HBV parameters (descale + derived constants) ----
        float beta  = 1.0f   + pr[0]  * 5.0f;
        float fc    = 50.0f  + pr[2]  * 950.0f;
        float k0    = 0.05f  + pr[4]  * 0.85f;
        float k1    = 0.01f  + pr[6]  * 0.49f;
        float k2    = 0.001f + pr[8]  * 0.199f;
        float lp    = 0.2f   + pr[10] * 0.8f;
        float perc  =          pr[12] * 10.0f;
        float uzl   =          pr[14] * 100.0f;
        float tt    = -2.5f  + pr[16] * 5.0f;
        float cfmax = 0.5f   + pr[18] * 9.5f;
        float cfr   =          pr[20] * 0.1f;
        float cwh   =          pr[22] * 0.2f;
        float invfc   = 1.0f / fc;
        float invlpfc = 1.0f / (lp * fc);
        float ncfrcf  = -(cfr * cfmax);
        float omk0    = 1.0f - k0;
        float k0uzl   = k0 * uzl;
        float omk1    = 1.0f - k1;

        float sp = 1e-5f, mw = 1e-5f, sm = 0.5f * fc, suz = 1e-5f, slz = 1e-5f;

        auto body = [&](float p, float tc, float pet) -> float {
            float dt   = tc - tt;
            float msn  = fmaxf(cfmax * dt, 0.0f);
            float mrf  = fmaxf(ncfrcf * dt, 0.0f);
            float rain = (dt >= 0.0f) ? p : 0.0f;
            float snow = p - rain;
            float etk  = fmaf(-invlpfc, pet, 1.0f);
            float sw   = exp2f(beta * __log2f(sm * invfc));
            float omsw = 1.0f - sw;
            float sp1  = sp + snow;
            float melt = fminf(msn, sp1);
            float mw2  = mw + melt;
            float sp2  = sp1 - melt;
            float refr = fminf(mrf, mw2);
            float mw3  = mw2 - refr;
            sp = sp2 + refr;
            float mw4  = fminf(mw3, cwh * sp);
            float tosoil = mw3 - mw4;
            mw = mw4;
            float rt    = rain + tosoil;
            float sm1   = fmaf(rt, omsw, sm);
            float rech  = rt * sw;
            float excess = fmaxf(sm1 - fc, 0.0f);
            float sm2   = fminf(sm1, fc);
            sm = fmaxf(fmaxf(sm2 * etk, sm2 - pet), 1e-5f);
            float suz1 = suz + rech + excess;
            float suz2 = fmaxf(suz1 - perc, 0.0f);
            float pa   = suz1 - suz2;
            float suz3 = fminf(suz2, fmaf(suz2, omk0, k0uzl));
            float suzn = omk1 * suz3;
            float q01  = suz2 - suzn;
            suz = suzn;
            float slz1 = slz + pa;
            float q2   = k2 * slz1;
            slz = slz1 - q2;
            return q01 + q2;
        };

        if (FUSED) {
            // 24 outer iters x 30 steps (t = 0..719, prefetch t+10 <= 729)
            for (int cc = 0; cc < 24; ++cc) {
#pragma unroll
                for (int j2 = 0; j2 < 30; ++j2) {
                    const int j = j2 % PD;
                    float p = pb[j], tc = tb[j], pet = eb[j];
                    pb[j] = x[xoff]; tb[j] = x[xoff + 1]; eb[j] = x[xoff + 2];
                    xoff += 3 * GG;
                    route_tail(body(p, tc, pet), j2 % LENF);
                }
            }
#pragma unroll
            for (int j = 0; j < PD; ++j)        // t = 720..729 (720%15 == 0)
                route_tail(body(pb[j], tb[j], eb[j]), j % LENF);
        } else {
            for (int c = 0; c < SS / PD - 1; ++c) {
#pragma unroll
                for (int j = 0; j < PD; ++j) {
                    float p = pb[j], tc = tb[j], pet = eb[j];
                    pb[j] = x[xoff]; tb[j] = x[xoff + 1]; eb[j] = x[xoff + 2];
                    xoff += 3 * GG;
                    atomicAdd(&qsim[qoff], 0.25f * body(p, tc, pet));
                    qoff += GG;
                }
            }
#pragma unroll
            for (int j = 0; j < PD; ++j) {
                atomicAdd(&qsim[qoff], 0.25f * body(pb[j], tb[j], eb[j]));
                qoff += GG;
            }
        }
    } else {
        // ---- EXP-HYDRO parameters (descale + derived constants) ----
        const float* pe = pr + 24;
        float f    =           pe[0]  * 0.1f;
        float smax = 100.0f  + pe[2]  * 1400.0f;
        float qmax = 10.0f   + pe[4]  * 40.0f;
        float df   =           pe[6]  * 5.0f;
        float tmax =           pe[8]  * 3.0f;
        float tmin = -3.0f   + pe[10] * 3.0f;
        float invsmax = 1.0f / smax;
        float fl = f * 1.44269504f;              // f * log2(e)
        float c0 = __log2f(qmax) - fl * smax;    // fold qmax into exponent

        float s0 = 1e-5f, s1 = 0.5f * smax;

        auto body = [&](float p, float tc, float pet) -> float {
            float mdf = df * fmaxf(tc - tmax, 0.0f);
            float ps  = (tc <= tmin) ? p : 0.0f;
            float prr = p - ps;
            float etk = fmaxf(fmaf(-invsmax, pet, 1.0f), 0.0f);
            float mlt = fminf(s0, mdf);
            s0 = fmaxf(s0 - mdf, 0.0f) + ps;
            float s1a = s1 + prr + mlt;
            float qspill = fmaxf(s1a - smax, 0.0f);
            float s1b = fminf(s1a, smax);
            float s1c = s1b * etk;
            float qb  = fminf(exp2f(fmaf(fl, s1c, c0)), s1c);
            s1 = s1c - qb;
            return qspill + qb;
        };

        if (FUSED) {
            for (int cc = 0; cc < 24; ++cc) {
#pragma unroll
                for (int j2 = 0; j2 < 30; ++j2) {
                    const int j = j2 % PD;
                    float p = pb[j], tc = tb[j], pet = eb[j];
                    pb[j] = x[xoff]; tb[j] = x[xoff + 1]; eb[j] = x[xoff + 2];
                    xoff += 3 * GG;
                    route_tail(body(p, tc, pet), j2 % LENF);
                }
            }
#pragma unroll
            for (int j = 0; j < PD; ++j)
                route_tail(body(pb[j], tb[j], eb[j]), j % LENF);
        } else {
            for (int c = 0; c < SS / PD - 1; ++c) {
#pragma unroll
                for (int j = 0; j < PD; ++j) {
                    float p = pb[j], tc = tb[j], pet = eb[j];
                    pb[j] = x[xoff]; tb[j] = x[xoff + 1]; eb[j] = x[xoff + 2];
                    xoff += 3 * GG;
                    atomicAdd(&qsim[qoff], 0.25f * body(p, tc, pet));
                    qoff += GG;
                }
            }
#pragma unroll
            for (int j = 0; j < PD; ++j) {
                atomicAdd(&qsim[qoff], 0.25f * body(pb[j], tb[j], eb[j]));
                qoff += GG;
            }
        }
    }
}

// ---------------------------------------------------------------------------
// Final sum: out = r0 + r1 + r2 + r3 (elementwise over the 4 routed-partial
// slices), float4-vectorized. SS*GG = 2.92e6 floats = 730000 float4.
// ---------------------------------------------------------------------------
__global__ __launch_bounds__(256) void sum4(const float* __restrict__ r,
                                            float* __restrict__ out) {
    int i = blockIdx.x * 256 + threadIdx.x;
    if (i >= (int)(QN / 4)) return;
    const float4* r0 = (const float4*)r;
    const float4* r1 = (const float4*)(r + QN);
    const float4* r2 = (const float4*)(r + 2 * QN);
    const float4* r3 = (const float4*)(r + 3 * QN);
    float4 a = r0[i], b = r1[i], c = r2[i], d = r3[i];
    float4 o;
    o.x = (a.x + b.x) + (c.x + d.x);
    o.y = (a.y + b.y) + (c.y + d.y);
    o.z = (a.z + b.z) + (c.z + d.z);
    o.w = (a.w + b.w) + (c.w + d.w);
    ((float4*)out)[i] = o;
}

// ---------------------------------------------------------------------------
// Atomic-fallback route (only used if d_ws is too small for 4 slices):
// computes weights inline, qsim is a single 0.25-scaled slice.
// ---------------------------------------------------------------------------
__global__ __launch_bounds__(256) void hydro_route1(const float* __restrict__ qsim,
                                                    const float* __restrict__ raw,
                                                    float* __restrict__ out) {
    int idx = blockIdx.x * 256 + threadIdx.x;
    if (idx >= GG * (SS / TT)) return;
    int g = idx % GG;
    int c = idx / GG;
    int t0 = c * TT;

    float a = raw[(size_t)g * 38 + 36] * 2.9f;
    float b = raw[(size_t)g * 38 + 37] * 6.5f;
    float aa = fmaxf(a, 0.0f) + 0.1f;
    float th = fmaxf(b, 0.0f) + 0.5f;
    float am1 = aa - 1.0f;
    float invth = 1.0f / th;
    const float logt[LENF] = {
        -0.69314718f, 0.40546511f, 0.91629073f, 1.25276297f, 1.50407740f,
         1.70474809f, 1.87180218f, 2.01490302f, 2.14006616f, 2.25129180f,
         2.35137526f, 2.44234704f, 2.52572864f, 2.60268969f, 2.67414865f };
    float w[LENF];
    float s = 0.0f;
#pragma unroll
    for (int k = 0; k < LENF; ++k) {
        float tk = (float)k + 0.5f;
        w[k] = expf(am1 * logt[k] - tk * invth);
        s += w[k];
    }
    float scale = 1.0f / s;

    float v[TT + LENF - 1];
#pragma unroll
    for (int i = 0; i < TT + LENF - 1; ++i) {
        int tp = t0 - (LENF - 1) + i;
        v[i] = (tp >= 0) ? qsim[(size_t)tp * GG + g] : 0.0f;
    }
#pragma unroll
    for (int j = 0; j < TT; ++j) {
        float acc = 0.0f;
#pragma unroll
        for (int k = 0; k < LENF; ++k)
            acc += w[k] * v[j + (LENF - 1) - k];
        out[(size_t)(t0 + j) * GG + g] = acc * scale;
    }
}

// ---------------------------------------------------------------------------
extern "C" void kernel_launch(void* const* d_in, const int* in_sizes, int n_in,
                              void* d_out, int out_size, void* d_ws, size_t ws_size,
                              hipStream_t stream) {
    const float* x   = (const float*)d_in[0];   // (730, 4000, 3) f32
    const float* raw = (const float*)d_in[1];   // (4000, 38) f32
    float* out  = (float*)d_out;                // (730, 4000) f32
    float* qsim = (float*)d_ws;

    const size_t slices4 = 4 * QN * sizeof(float);
    int sblocks = (4 * GPAD) / 64;

    if (ws_size >= slices4) {
        hydro_scan<true><<<sblocks, 64, 0, stream>>>(x, raw, qsim);
        sum4<<<((int)(QN / 4) + 255) / 256, 256, 0, stream>>>(qsim, out);
    } else {
        hipMemsetAsync(qsim, 0, QN * sizeof(float), stream);
        hydro_scan<false><<<sblocks, 64, 0, stream>>>(x, raw, qsim);
        hydro_route1<<<(GG * (SS / TT) + 255) / 256, 256, 0, stream>>>(qsim, raw, out);
    }
}